// Round 3
// baseline (480.544 us; speedup 1.0000x reference)
//
#include <hip/hip_runtime.h>
#include <hip/hip_bf16.h>

#define S 2048
#define D 1024
#define NH 16
#define HD 64
#define NE 65536
#define DH 512

typedef __attribute__((ext_vector_type(8))) short short8;
typedef __attribute__((ext_vector_type(4))) float f32x4;

#define MFMA16(a, b, c) __builtin_amdgcn_mfma_f32_16x16x32_bf16(a, b, c, 0, 0, 0)

__device__ __forceinline__ unsigned short f2bf(float f) {
    __hip_bfloat16 h = __float2bfloat16(f);
    return *reinterpret_cast<unsigned short*>(&h);
}

// ---------------- prep: fp32 -> bf16 conversions ----------------
__global__ __launch_bounds__(256) void k_convert_x(const float* __restrict__ x,
                                                   unsigned short* __restrict__ xb) {
    int i = (blockIdx.x * 256 + threadIdx.x) * 4;
    const float4 v = *reinterpret_cast<const float4*>(x + i);
    xb[i + 0] = f2bf(v.x);
    xb[i + 1] = f2bf(v.y);
    xb[i + 2] = f2bf(v.z);
    xb[i + 3] = f2bf(v.w);
}

// 5 weight slots (2MB bf16 each): 0=Wq 1=Wk 2=Wv 3=Wn1[:, :1024] 4=Wo
__global__ __launch_bounds__(256) void k_convert_w(const float* __restrict__ Wq,
                                                   const float* __restrict__ Wk,
                                                   const float* __restrict__ Wv,
                                                   const float* __restrict__ Wn1,
                                                   const float* __restrict__ Wo,
                                                   unsigned short* __restrict__ wb) {
    int row = blockIdx.x, mat = blockIdx.y, t = threadIdx.x;
    if (mat == 3 && row >= DH) return;
    const float* src;
    long stride = 1024;
    if (mat == 0) src = Wq;
    else if (mat == 1) src = Wk;
    else if (mat == 2) src = Wv;
    else if (mat == 3) { src = Wn1; stride = 1026; }
    else src = Wo;
    const float* r = src + (long)row * stride;
    unsigned short* o = wb + (long)mat * 1048576 + (long)row * 1024;
#pragma unroll
    for (int j = 0; j < 4; j++) o[t * 4 + j] = f2bf(r[t * 4 + j]);
}

// ---------------- stoich mask scatter (numpy last-wins) ----------------
__global__ __launch_bounds__(256) void k_scatter_max(const int* __restrict__ ei,
                                                     int* __restrict__ order) {
    int e = blockIdx.x * 256 + threadIdx.x;
    int r = ei[e], c = ei[NE + e];
    atomicMax(&order[r * S + c], e + 1);
}

__global__ __launch_bounds__(256) void k_scatter_write(const int* __restrict__ ei,
                                                       const float* __restrict__ st,
                                                       const int* __restrict__ order,
                                                       float* __restrict__ mask) {
    int e = blockIdx.x * 256 + threadIdx.x;
    int r = ei[e], c = ei[NE + e];
    int slot = r * S + c;
    if (order[slot] == e + 1) mask[slot] = st[e];
}

// ---------------- fused QKV + hidden GEMM ----------------
// z=0: Q -> [h][s][hd] bf16   z=1: K -> [h][s][hd] bf16
// z=2: V -> [h][hd][s] bf16 (transposed)   z=3: hidden (N=512) -> fp32 [s][512]
__global__ __launch_bounds__(256) void k_gemm_qkvh(const unsigned short* __restrict__ xb,
                                                   const unsigned short* __restrict__ wb,
                                                   const float* __restrict__ bq,
                                                   const float* __restrict__ bk,
                                                   const float* __restrict__ bv,
                                                   const float* __restrict__ bn1,
                                                   unsigned short* __restrict__ qout,
                                                   unsigned short* __restrict__ kout,
                                                   unsigned short* __restrict__ vtout,
                                                   float* __restrict__ hidden) {
    const int z = blockIdx.z;
    if (z == 3 && blockIdx.y >= 8) return;
    const int tid = threadIdx.x, w = tid >> 6, lane = tid & 63;
    const int l15 = lane & 15, lhi = lane >> 4;
    const int m0 = blockIdx.x * 64 + w * 16;
    const int n0 = blockIdx.y * 64;
    const unsigned short* W = wb + (long)z * 1048576;
    f32x4 acc[4];
#pragma unroll
    for (int t = 0; t < 4; t++) acc[t] = (f32x4){0.f, 0.f, 0.f, 0.f};
    const unsigned short* ap0 = xb + (long)(m0 + l15) * 1024 + lhi * 8;
    const unsigned short* bp0 = W + (long)(n0 + l15) * 1024 + lhi * 8;
    for (int kc = 0; kc < 32; kc++) {
        short8 a = *reinterpret_cast<const short8*>(ap0 + kc * 32);
#pragma unroll
        for (int t = 0; t < 4; t++) {
            short8 b = *reinterpret_cast<const short8*>(bp0 + (long)t * 16 * 1024 + kc * 32);
            acc[t] = MFMA16(a, b, acc[t]);
        }
    }
    const float* bias = (z == 0) ? bq : ((z == 1) ? bk : ((z == 2) ? bv : bn1));
#pragma unroll
    for (int t = 0; t < 4; t++) {
        int n = n0 + t * 16 + l15;
        float bb = bias[n];
#pragma unroll
        for (int r = 0; r < 4; r++) {
            int m = m0 + lhi * 4 + r;
            float v = acc[t][r] + bb;
            if (z == 3) {
                hidden[(long)m * DH + n] = v;
            } else {
                unsigned short bits = f2bf(v);
                int hh = n >> 6, hd = n & 63;
                if (z == 0) qout[(long)hh * S * HD + (long)m * HD + hd] = bits;
                else if (z == 1) kout[(long)hh * S * HD + (long)m * HD + hd] = bits;
                else vtout[(long)hh * S * HD + (long)hd * S + m] = bits;
            }
        }
    }
}

// ---------------- node-type MLP tail -> ntwT [h][s] (transposed for attention) ----------------
__global__ __launch_bounds__(256) void k_ntw(const float* __restrict__ hidden,
                                             const float* __restrict__ Wn1,
                                             const float* __restrict__ nt,
                                             const float* __restrict__ Wn2,
                                             const float* __restrict__ bn2,
                                             float* __restrict__ ntwT) {
    int s = blockIdx.x, tid = threadIdx.x;
    __shared__ float rh[DH];
    __shared__ float part[16][17];
    float nt0 = nt[s * 2 + 0], nt1 = nt[s * 2 + 1];
    for (int j = tid; j < DH; j += 256) {
        float v = hidden[(long)s * DH + j] + nt0 * Wn1[(long)j * 1026 + 1024]
                + nt1 * Wn1[(long)j * 1026 + 1025];
        rh[j] = fmaxf(v, 0.f);
    }
    __syncthreads();
    {
        int hh = tid & 15, ch = tid >> 4;
        float p = 0.f;
#pragma unroll
        for (int j = 0; j < 32; j++) p += rh[ch * 32 + j] * Wn2[hh * DH + ch * 32 + j];
        part[ch][hh] = p;
    }
    __syncthreads();
    if (tid < 16) {
        float l = bn2[tid];
#pragma unroll
        for (int c = 0; c < 16; c++) l += part[c][tid];
        float mx = l;
#pragma unroll
        for (int m = 1; m < 16; m <<= 1) mx = fmaxf(mx, __shfl_xor(mx, m));
        float e = __expf(l - mx);
        float sum = e;
#pragma unroll
        for (int m = 1; m < 16; m <<= 1) sum += __shfl_xor(sum, m);
        ntwT[tid * S + s] = e / sum;
    }
}

// ---------------- attention v3: two-pass online softmax, no score storage ----------------
// Block: 16 q-rows x 1 head, 4 waves; wave w owns keys [w*512, w*512+512) in 16
// chunks of 32. Swapped MFMA(K,Q) with PERMUTED K-row loading: within each
// 32-key chunk, tile A covers keys {8g+0..3}, tile B {8g+4..7} (g = lane>>4),
// so lane (q=lane&15, g) ends up holding keys 8g..8g+7 — exactly the 16x16x32
// A-fragment layout for PV. No LDS transpose. Pass 1 computes online (m,sum);
// pass 2 recomputes scores, writes attn, and accumulates PV.
__global__ __launch_bounds__(256, 4) void k_attn(const unsigned short* __restrict__ qb,
                                                 const unsigned short* __restrict__ kb,
                                                 const unsigned short* __restrict__ vtb,
                                                 const float* __restrict__ ntwT,
                                                 const float* __restrict__ mask,
                                                 float* __restrict__ attn_out,
                                                 unsigned short* __restrict__ pv_out) {
    __shared__ float redm[4][16];
    __shared__ float reds[4][16];
    __shared__ float pvp[4][16][68];

    const int tid = threadIdx.x, w = tid >> 6, lane = tid & 63;
    const int l15 = lane & 15, g = lane >> 4;
    // XCD-aware remap: 2048 blocks, 8 XCDs -> each XCD gets 2 consecutive heads
    int bid = ((int)blockIdx.x & 7) * 256 + ((int)blockIdx.x >> 3);
    const int h = bid >> 7, q0 = (bid & 127) * 16;
    const long hoff = (long)h * S * HD;

    // Q as B-operand: lane holds Q[q0+l15][8g..8g+7]
    const unsigned short* qp = qb + hoff + (long)(q0 + l15) * HD + g * 8;
    const short8 qf0 = *reinterpret_cast<const short8*>(qp);
    const short8 qf1 = *reinterpret_cast<const short8*>(qp + 32);

    // permuted K row for tile A: rowA = 8*(l15>>2) + (l15&3); tile B: rowA+4
    const int rowA = 8 * (l15 >> 2) + (l15 & 3);
    const unsigned short* kbaseA = kb + hoff + (long)(w * 512 + rowA) * HD + g * 8;
    const unsigned short* kbaseB = kbaseA + 4 * HD;
    const float* mrow = mask + (long)(q0 + l15) * S + w * 512 + 8 * g;
    const float* nrow = ntwT + (long)h * S + w * 512 + 8 * g;

    // ---- pass 1: online max/sum ----
    float m = -3.0e38f, sum = 0.f;
#pragma unroll 4
    for (int cc = 0; cc < 16; cc++) {
        const unsigned short* kpA = kbaseA + cc * 32 * HD;
        const unsigned short* kpB = kbaseB + cc * 32 * HD;
        short8 a0 = *reinterpret_cast<const short8*>(kpA);
        short8 a1 = *reinterpret_cast<const short8*>(kpA + 32);
        short8 b0 = *reinterpret_cast<const short8*>(kpB);
        short8 b1 = *reinterpret_cast<const short8*>(kpB + 32);
        f32x4 cA = (f32x4){0.f, 0.f, 0.f, 0.f};
        cA = MFMA16(a0, qf0, cA);
        cA = MFMA16(a1, qf1, cA);
        f32x4 cB = (f32x4){0.f, 0.f, 0.f, 0.f};
        cB = MFMA16(b0, qf0, cB);
        cB = MFMA16(b1, qf1, cB);
        f32x4 mA = *reinterpret_cast<const f32x4*>(mrow + cc * 32);
        f32x4 mB = *reinterpret_cast<const f32x4*>(mrow + cc * 32 + 4);
        f32x4 nA = *reinterpret_cast<const f32x4*>(nrow + cc * 32);
        f32x4 nB = *reinterpret_cast<const f32x4*>(nrow + cc * 32 + 4);
        f32x4 sA = cA * mA * nA * 0.125f;
        f32x4 sB = cB * mB * nB * 0.125f;
        float tm = fmaxf(fmaxf(fmaxf(sA[0], sA[1]), fmaxf(sA[2], sA[3])),
                         fmaxf(fmaxf(sB[0], sB[1]), fmaxf(sB[2], sB[3])));
        float mn = fmaxf(m, tm);
        float msc = __expf(m - mn);
        float es = __expf(sA[0] - mn) + __expf(sA[1] - mn) + __expf(sA[2] - mn)
                 + __expf(sA[3] - mn) + __expf(sB[0] - mn) + __expf(sB[1] - mn)
                 + __expf(sB[2] - mn) + __expf(sB[3] - mn);
        sum = sum * msc + es;
        m = mn;
    }
    // merge across the 4 lane-groups (g) holding the same q
#pragma unroll
    for (int off = 16; off < 64; off <<= 1) {
        float mo = __shfl_xor(m, off);
        float so = __shfl_xor(sum, off);
        float mn = fmaxf(m, mo);
        sum = sum * __expf(m - mn) + so * __expf(mo - mn);
        m = mn;
    }
    if (lane < 16) { redm[w][lane] = m; reds[w][lane] = sum; }
    __syncthreads();
    const float m0 = redm[0][l15], m1 = redm[1][l15], m2 = redm[2][l15], m3 = redm[3][l15];
    const float gm = fmaxf(fmaxf(m0, m1), fmaxf(m2, m3));
    const float gs = reds[0][l15] * __expf(m0 - gm) + reds[1][l15] * __expf(m1 - gm)
                   + reds[2][l15] * __expf(m2 - gm) + reds[3][l15] * __expf(m3 - gm);
    const float inv = 1.0f / gs;

    // ---- pass 2: recompute scores, write attn, PV ----
    float* arow = attn_out + ((long)h * S + q0 + l15) * S + w * 512 + 8 * g;
    const unsigned short* vbase = vtb + hoff + (long)l15 * S + w * 512 + 8 * g;
    f32x4 acc[4];
#pragma unroll
    for (int t = 0; t < 4; t++) acc[t] = (f32x4){0.f, 0.f, 0.f, 0.f};

#pragma unroll 2
    for (int cc = 0; cc < 16; cc++) {
        const unsigned short* kpA = kbaseA + cc * 32 * HD;
        const unsigned short* kpB = kbaseB + cc * 32 * HD;
        short8 a0 = *reinterpret_cast<const short8*>(kpA);
        short8 a1 = *reinterpret_cast<const short8*>(kpA + 32);
        short8 b0 = *reinterpret_cast<const short8*>(kpB);
        short8 b1 = *reinterpret_cast<const short8*>(kpB + 32);
        f32x4 cA = (f32x4){0.f, 0.f, 0.f, 0.f};
        cA = MFMA16(a0, qf0, cA);
        cA = MFMA16(a1, qf1, cA);
        f32x4 cB = (f32x4){0.f, 0.f, 0.f, 0.f};
        cB = MFMA16(b0, qf0, cB);
        cB = MFMA16(b1, qf1, cB);
        f32x4 mA = *reinterpret_cast<const f32x4*>(mrow + cc * 32);
        f32x4 mB = *reinterpret_cast<const f32x4*>(mrow + cc * 32 + 4);
        f32x4 nA = *reinterpret_cast<const f32x4*>(nrow + cc * 32);
        f32x4 nB = *reinterpret_cast<const f32x4*>(nrow + cc * 32 + 4);
        f32x4 sA = cA * mA * nA * 0.125f;
        f32x4 sB = cB * mB * nB * 0.125f;
        f32x4 pA, pB;
#pragma unroll
        for (int j = 0; j < 4; j++) {
            pA[j] = __expf(sA[j] - gm) * inv;
            pB[j] = __expf(sB[j] - gm) * inv;
        }
        *reinterpret_cast<f32x4*>(arow + cc * 32) = pA;
        *reinterpret_cast<f32x4*>(arow + cc * 32 + 4) = pB;
        short8 pa;
#pragma unroll
        for (int j = 0; j < 4; j++) {
            pa[j] = (short)f2bf(pA[j]);
            pa[4 + j] = (short)f2bf(pB[j]);
        }
        const unsigned short* vp = vbase + cc * 32;
#pragma unroll
        for (int t2 = 0; t2 < 4; t2++) {
            short8 vf = *reinterpret_cast<const short8*>(vp + (long)t2 * 16 * S);
            acc[t2] = MFMA16(pa, vf, acc[t2]);
        }
    }

    // per-wave PV partials -> LDS -> reduce -> bf16 store
#pragma unroll
    for (int t2 = 0; t2 < 4; t2++)
#pragma unroll
        for (int r = 0; r < 4; r++)
            pvp[w][4 * g + r][t2 * 16 + l15] = acc[t2][r];
    __syncthreads();
#pragma unroll
    for (int u = 0; u < 4; u++) {
        int idx = u * 256 + tid;
        int q = idx >> 6, hd = idx & 63;
        float v = pvp[0][q][hd] + pvp[1][q][hd] + pvp[2][q][hd] + pvp[3][q][hd];
        pv_out[(long)(q0 + q) * D + h * HD + hd] = f2bf(v);
    }
}

// ---------------- out projection GEMM (bf16 A) ----------------
__global__ __launch_bounds__(256) void k_gemm_out(const unsigned short* __restrict__ A,
                                                  const unsigned short* __restrict__ wo,
                                                  const float* __restrict__ bo,
                                                  float* __restrict__ proj) {
    const int tid = threadIdx.x, w = tid >> 6, lane = tid & 63;
    const int l15 = lane & 15, lhi = lane >> 4;
    const int m0 = blockIdx.x * 64 + w * 16;
    const int n0 = blockIdx.y * 64;
    f32x4 acc[4];
#pragma unroll
    for (int t = 0; t < 4; t++) acc[t] = (f32x4){0.f, 0.f, 0.f, 0.f};
    const unsigned short* ap0 = A + (long)(m0 + l15) * 1024 + lhi * 8;
    const unsigned short* bp0 = wo + (long)(n0 + l15) * 1024 + lhi * 8;
    for (int kc = 0; kc < 32; kc++) {
        short8 a = *reinterpret_cast<const short8*>(ap0 + kc * 32);
#pragma unroll
        for (int t = 0; t < 4; t++) {
            short8 b = *reinterpret_cast<const short8*>(bp0 + (long)t * 16 * 1024 + kc * 32);
            acc[t] = MFMA16(a, b, acc[t]);
        }
    }
#pragma unroll
    for (int t = 0; t < 4; t++) {
        int n = n0 + t * 16 + l15;
        float bb = bo[n];
#pragma unroll
        for (int r = 0; r < 4; r++) {
            int m = m0 + lhi * 4 + r;
            proj[(long)m * 1024 + n] = acc[t][r] + bb;
        }
    }
}

// ---------------- residual + LayerNorm ----------------
__global__ __launch_bounds__(256) void k_ln(const float* __restrict__ x,
                                            const float* __restrict__ proj,
                                            const float* __restrict__ g,
                                            const float* __restrict__ bta,
                                            float* __restrict__ y) {
    int s = blockIdx.x, tid = threadIdx.x;
    int w = tid >> 6, lane = tid & 63;
    __shared__ float red[8];
    float4 xv = reinterpret_cast<const float4*>(x + (long)s * 1024)[tid];
    float4 pv = reinterpret_cast<const float4*>(proj + (long)s * 1024)[tid];
    float t0 = xv.x + pv.x, t1 = xv.y + pv.y, t2 = xv.z + pv.z, t3 = xv.w + pv.w;
    float lsum = t0 + t1 + t2 + t3;
#pragma unroll
    for (int m = 32; m >= 1; m >>= 1) lsum += __shfl_xor(lsum, m);
    if (lane == 0) red[w] = lsum;
    __syncthreads();
    float mean = (red[0] + red[1] + red[2] + red[3]) * (1.0f / 1024.f);
    float d0 = t0 - mean, d1 = t1 - mean, d2 = t2 - mean, d3 = t3 - mean;
    float lvar = d0 * d0 + d1 * d1 + d2 * d2 + d3 * d3;
#pragma unroll
    for (int m = 32; m >= 1; m >>= 1) lvar += __shfl_xor(lvar, m);
    if (lane == 0) red[4 + w] = lvar;
    __syncthreads();
    float var = (red[4] + red[5] + red[6] + red[7]) * (1.0f / 1024.f);
    float rstd = rsqrtf(var + 1e-5f);
    float4 gv = reinterpret_cast<const float4*>(g)[tid];
    float4 bv = reinterpret_cast<const float4*>(bta)[tid];
    float4 out;
    out.x = d0 * rstd * gv.x + bv.x;
    out.y = d1 * rstd * gv.y + bv.y;
    out.z = d2 * rstd * gv.z + bv.z;
    out.w = d3 * rstd * gv.w + bv.w;
    reinterpret_cast<float4*>(y + (long)s * 1024)[tid] = out;
}

extern "C" void kernel_launch(void* const* d_in, const int* in_sizes, int n_in,
                              void* d_out, int out_size, void* d_ws, size_t ws_size,
                              hipStream_t stream) {
    const float* x = (const float*)d_in[0];
    const float* node_types = (const float*)d_in[1];
    const float* stoich = (const float*)d_in[2];
    const float* Wq = (const float*)d_in[3];
    const float* bq = (const float*)d_in[4];
    const float* Wk = (const float*)d_in[5];
    const float* bk = (const float*)d_in[6];
    const float* Wv = (const float*)d_in[7];
    const float* bv = (const float*)d_in[8];
    const float* Wo = (const float*)d_in[9];
    const float* bo = (const float*)d_in[10];
    const float* Wn1 = (const float*)d_in[11];
    const float* bn1 = (const float*)d_in[12];
    const float* Wn2 = (const float*)d_in[13];
    const float* bn2 = (const float*)d_in[14];
    const float* ln_g = (const float*)d_in[15];
    const float* ln_b = (const float*)d_in[16];
    const int* ei = (const int*)d_in[17];

    char* ws = (char*)d_ws;
    unsigned short* x_bf = (unsigned short*)(ws);                // 0..4M
    unsigned short* q_bf = (unsigned short*)(ws + (4l << 20));   // 4..8M  [h][s][hd]
    unsigned short* k_bf = (unsigned short*)(ws + (8l << 20));   // 8..12M [h][s][hd]
    unsigned short* vt_bf = (unsigned short*)(ws + (12l << 20)); // 12..16M [h][hd][s]
    unsigned short* w_bf = (unsigned short*)(ws + (16l << 20));  // 16..26M 5 slots
    float* hidden = (float*)(ws + (26l << 20));                  // 26..30M
    float* ntwT = (float*)(ws + (30l << 20));                    // 30M (128KB) [h][s]
    float* mask = (float*)(ws + (31l << 20));                    // 31..47M
    int* order = (int*)(ws + (47l << 20));                       // 47..63M (scatter only)
    unsigned short* pvb = (unsigned short*)(ws + (47l << 20));   // 47..51M bf16 (aliases order)
    float* proj = (float*)(ws + (55l << 20));                    // 55..63M

    float* y_out = (float*)d_out;
    float* attn_out = (float*)d_out + (long)S * D;  // 2097152

    hipMemsetAsync(mask, 0, 16l << 20, stream);
    hipMemsetAsync(order, 0, 16l << 20, stream);
    k_convert_x<<<2048, 256, 0, stream>>>(x, x_bf);
    k_convert_w<<<dim3(1024, 5), 256, 0, stream>>>(Wq, Wk, Wv, Wn1, Wo, w_bf);
    k_scatter_max<<<256, 256, 0, stream>>>(ei, order);
    k_scatter_write<<<256, 256, 0, stream>>>(ei, stoich, order, mask);
    k_gemm_qkvh<<<dim3(32, 16, 4), 256, 0, stream>>>(x_bf, w_bf, bq, bk, bv, bn1,
                                                     q_bf, k_bf, vt_bf, hidden);
    k_ntw<<<2048, 256, 0, stream>>>(hidden, Wn1, node_types, Wn2, bn2, ntwT);
    k_attn<<<2048, 256, 0, stream>>>(q_bf, k_bf, vt_bf, ntwT, mask,
                                     attn_out, pvb);
    k_gemm_out<<<dim3(32, 16), 256, 0, stream>>>(pvb, w_bf + 4l * 1048576, bo, proj);
    k_ln<<<2048, 256, 0, stream>>>(x, proj, ln_g, ln_b, y_out);
}